// Round 1
// baseline (707.829 us; speedup 1.0000x reference)
//
#include <hip/hip_runtime.h>
#include <hip/hip_bf16.h>

typedef __attribute__((ext_vector_type(4))) float f32x4;
typedef __attribute__((ext_vector_type(8))) short short8;

#define HH 512
#define BB 32
#define SS 2048
#define KK 1024  // 2H

__device__ __forceinline__ unsigned short f2bf(float f) {
    // round-to-nearest-even fp32 -> bf16 (no NaN inputs here)
    unsigned int u = __float_as_uint(f);
    u += 0x7fffu + ((u >> 16) & 1u);
    return (unsigned short)(u >> 16);
}

__device__ __forceinline__ float fast_tanh(float x) {
    // tanh(x) = 1 - 2/(exp(2x)+1); exact at both saturation ends
    float e = __expf(2.0f * x);
    return 1.0f - 2.0f / (e + 1.0f);
}

// ---------------- kernel 1: spb[b][h] = output[b]·W_s[h] + b_attn[h] ----------------
__global__ void spb_kernel(const float* __restrict__ out_state,
                           const float* __restrict__ W,
                           const float* __restrict__ bias,
                           float* __restrict__ spb) {
    __shared__ float ov[HH];
    int b = blockIdx.x;
    for (int i = threadIdx.x; i < HH; i += 256) ov[i] = out_state[b * HH + i];
    __syncthreads();
    for (int h = threadIdx.x; h < HH; h += 256) {
        const float* wr = W + (size_t)h * 1536;  // W_s row h = W_attn[h, 0:512]
        float acc = 0.f;
        for (int k = 0; k < HH; k += 4) {
            float4 w = *(const float4*)(wr + k);
            acc += ov[k] * w.x + ov[k + 1] * w.y + ov[k + 2] * w.z + ov[k + 3] * w.w;
        }
        spb[b * HH + h] = acc + bias[h];
    }
}

// ---------------- kernel 2: W_e -> bf16, K-tiled layout Wt[kt][h][32] ----------------
__global__ void wconv_kernel(const float* __restrict__ W, unsigned short* __restrict__ Wt) {
    int idx = blockIdx.x * 256 + threadIdx.x;  // 131072 threads, 4 elems each
    int e4 = idx * 4;
    int h = e4 >> 10;        // [0,512)
    int k = e4 & 1023;       // [0,1024), multiple of 4
    float4 w = *(const float4*)(W + (size_t)h * 1536 + 512 + k);
    int kt = k >> 5, kk = k & 31;
    ushort4 p;
    p.x = f2bf(w.x); p.y = f2bf(w.y); p.z = f2bf(w.z); p.w = f2bf(w.w);
    *(ushort4*)(Wt + (size_t)kt * (512 * 32) + h * 32 + kk) = p;
}

// ---------------- kernel 3: fused GEMM + tanh + v-dot -> scores[b][s] ----------------
// block: 256 thr (4 waves). Tile: M=64 rows (one b, 64 consecutive s) x N=512 (full H).
// wave w computes cols [w*128, w*128+128). K-loop BK=32, mfma_f32_16x16x32_bf16.
__global__ __launch_bounds__(256, 2)
void attn_gemm(const float* __restrict__ enc, const unsigned short* __restrict__ Wt,
               const float* __restrict__ spb, const float* __restrict__ vvec,
               float* __restrict__ scores) {
    __shared__ unsigned short Asm[64 * 32];    // 4 KB
    __shared__ unsigned short Bsm[512 * 32];   // 32 KB
    __shared__ float red[4][64];               // 1 KB

    const int tid = threadIdx.x;
    const int wave = tid >> 6;
    const int lane = tid & 63;
    const int r = lane & 15;   // frag row/col selector
    const int q = lane >> 4;   // k-quad
    const int blk = blockIdx.x;
    const int b = blk >> 5;          // 32 s-tiles per batch
    const int s0 = (blk & 31) << 6;  // 64 rows per tile

    // A staging: thread covers chunk tid: row=tid>>2, 8 floats at k-offset (tid&3)*8
    const int arow = tid >> 2;
    const int akq = tid & 3;
    const float4* aptr = (const float4*)(enc + ((size_t)(b * SS + s0 + arow)) * KK + akq * 8);

    f32x4 acc[4][8] = {};

    for (int kt = 0; kt < 32; ++kt) {
        // issue global loads before the barrier (overlap with other waves' compute)
        float4 f0 = aptr[0];
        float4 f1 = aptr[1];
        aptr += 8;  // advance 32 floats
        int4 bch[8];
        const int4* bs = (const int4*)(Wt + (size_t)kt * 16384);
        #pragma unroll
        for (int i = 0; i < 8; ++i) bch[i] = bs[tid + i * 256];

        __syncthreads();  // previous iteration's frag reads complete

        union { int4 v; unsigned short u[8]; } pk;
        pk.u[0] = f2bf(f0.x); pk.u[1] = f2bf(f0.y); pk.u[2] = f2bf(f0.z); pk.u[3] = f2bf(f0.w);
        pk.u[4] = f2bf(f1.x); pk.u[5] = f2bf(f1.y); pk.u[6] = f2bf(f1.z); pk.u[7] = f2bf(f1.w);
        *(int4*)((char*)Asm + tid * 16) = pk.v;  // contiguous: (tid>>2)*64 + (tid&3)*16
        #pragma unroll
        for (int i = 0; i < 8; ++i) {
            int c = tid + i * 256;
            *(int4*)((char*)Bsm + c * 16) = bch[i];  // contiguous layout
        }

        __syncthreads();

        short8 af[4], bf[8];
        #pragma unroll
        for (int mt = 0; mt < 4; ++mt)
            af[mt] = *(const short8*)(Asm + (mt * 16 + r) * 32 + q * 8);
        #pragma unroll
        for (int nf = 0; nf < 8; ++nf)
            bf[nf] = *(const short8*)(Bsm + (wave * 128 + nf * 16 + r) * 32 + q * 8);
        #pragma unroll
        for (int mt = 0; mt < 4; ++mt)
            #pragma unroll
            for (int nf = 0; nf < 8; ++nf)
                acc[mt][nf] = __builtin_amdgcn_mfma_f32_16x16x32_bf16(
                    af[mt], bf[nf], acc[mt][nf], 0, 0, 0);
    }

    // ---- epilogue: score partial = sum_h v[h]*tanh(ep + spb[b,h]) over this wave's cols
    float vh[8], sh[8];
    #pragma unroll
    for (int nf = 0; nf < 8; ++nf) {
        int h = wave * 128 + nf * 16 + r;  // this lane's col for frag nf
        vh[nf] = vvec[h];
        sh[nf] = spb[b * HH + h];
    }
    float rowacc[4][4] = {};
    #pragma unroll
    for (int mt = 0; mt < 4; ++mt)
        #pragma unroll
        for (int nf = 0; nf < 8; ++nf)
            #pragma unroll
            for (int i = 0; i < 4; ++i) {
                float x = acc[mt][nf][i] + sh[nf];
                rowacc[mt][i] += vh[nf] * fast_tanh(x);
            }
    // reduce over the 16 cols held by lanes sharing q (low 4 lane bits)
    #pragma unroll
    for (int mt = 0; mt < 4; ++mt)
        #pragma unroll
        for (int i = 0; i < 4; ++i) {
            float t = rowacc[mt][i];
            t += __shfl_xor(t, 1);
            t += __shfl_xor(t, 2);
            t += __shfl_xor(t, 4);
            t += __shfl_xor(t, 8);
            rowacc[mt][i] = t;
        }
    if (r == 0) {
        #pragma unroll
        for (int mt = 0; mt < 4; ++mt)
            #pragma unroll
            for (int i = 0; i < 4; ++i)
                red[wave][mt * 16 + q * 4 + i] = rowacc[mt][i];  // row = mt*16 + q*4 + i
    }
    __syncthreads();
    if (tid < 64) {
        float sum = red[0][tid] + red[1][tid] + red[2][tid] + red[3][tid];
        scores[b * SS + s0 + tid] = sum;
    }
}

// ---------------- kernel 4: masked softmax over S per batch ----------------
__global__ void softmax_kernel(const float* __restrict__ scores,
                               const int* __restrict__ mask,
                               float* __restrict__ out) {
    __shared__ float red[256];
    int b = blockIdx.x, tid = threadIdx.x;
    float x[8];
    #pragma unroll
    for (int i = 0; i < 8; ++i) {
        int s = tid + i * 256;
        float sc = scores[b * SS + s];
        if (mask[b * SS + s] == 0) sc -= 1000.0f;
        x[i] = sc;
    }
    float mx = x[0];
    #pragma unroll
    for (int i = 1; i < 8; ++i) mx = fmaxf(mx, x[i]);
    red[tid] = mx;
    __syncthreads();
    for (int o = 128; o > 0; o >>= 1) {
        if (tid < o) red[tid] = fmaxf(red[tid], red[tid + o]);
        __syncthreads();
    }
    mx = red[0];
    __syncthreads();
    float e[8], sum = 0.f;
    #pragma unroll
    for (int i = 0; i < 8; ++i) { e[i] = __expf(x[i] - mx); sum += e[i]; }
    red[tid] = sum;
    __syncthreads();
    for (int o = 128; o > 0; o >>= 1) {
        if (tid < o) red[tid] += red[tid + o];
        __syncthreads();
    }
    float inv = 1.0f / red[0];
    #pragma unroll
    for (int i = 0; i < 8; ++i) out[b * SS + tid + i * 256] = e[i] * inv;
}

extern "C" void kernel_launch(void* const* d_in, const int* in_sizes, int n_in,
                              void* d_out, int out_size, void* d_ws, size_t ws_size,
                              hipStream_t stream) {
    const float* out_state = (const float*)d_in[0];   // (32, 512)
    const float* enc       = (const float*)d_in[1];   // (32, 2048, 1024)
    const int*   mask      = (const int*)d_in[2];     // (32, 2048)
    const float* W_attn    = (const float*)d_in[3];   // (512, 1536)
    const float* b_attn    = (const float*)d_in[4];   // (512,)
    const float* vvec      = (const float*)d_in[5];   // (512,)
    float* out = (float*)d_out;                       // (32, 1, 2048)

    char* ws = (char*)d_ws;
    float*          spb    = (float*)ws;                         // 32*512*4   = 64 KB
    unsigned short* Wt     = (unsigned short*)(ws + 65536);      // 512*1024*2 = 1 MB
    float*          scores = (float*)(ws + 65536 + 1048576);     // 32*2048*4  = 256 KB

    spb_kernel<<<32, 256, 0, stream>>>(out_state, W_attn, b_attn, spb);
    wconv_kernel<<<512, 256, 0, stream>>>(W_attn, Wt);
    attn_gemm<<<1024, 256, 0, stream>>>(enc, Wt, spb, vvec, scores);
    softmax_kernel<<<32, 256, 0, stream>>>(scores, mask, out);
}

// Round 2
// 431.750 us; speedup vs baseline: 1.6394x; 1.6394x over previous
//
#include <hip/hip_runtime.h>
#include <hip/hip_bf16.h>

typedef __attribute__((ext_vector_type(4))) float f32x4;
typedef __attribute__((ext_vector_type(8))) short short8;

#define HH 512
#define BB 32
#define SS 2048
#define KK 1024  // 2H

__device__ __forceinline__ unsigned short f2bf(float f) {
    unsigned int u = __float_as_uint(f);
    u += 0x7fffu + ((u >> 16) & 1u);
    return (unsigned short)(u >> 16);
}

__device__ __forceinline__ float fast_tanh(float x) {
    float e = __expf(2.0f * x);
    return 1.0f - 2.0f / (e + 1.0f);
}

// ---------------- kernel 1: spb[b][h] = output[b]·W_s[h] + b_attn[h] ----------------
// one wave per (b,h): lanes stride along k -> coalesced W row reads
__global__ __launch_bounds__(256)
void spb_kernel(const float* __restrict__ out_state,
                const float* __restrict__ W,
                const float* __restrict__ bias,
                float* __restrict__ spb) {
    int wave = threadIdx.x >> 6, lane = threadIdx.x & 63;
    int g = blockIdx.x * 4 + wave;       // 16384 (b,h) pairs
    int b = g >> 9, h = g & 511;
    const float* wr = W + (size_t)h * 1536;      // W_s row h
    const float* ov = out_state + b * HH;
    float4 w0 = *(const float4*)(wr + lane * 8);
    float4 w1 = *(const float4*)(wr + lane * 8 + 4);
    float4 o0 = *(const float4*)(ov + lane * 8);
    float4 o1 = *(const float4*)(ov + lane * 8 + 4);
    float d = w0.x * o0.x + w0.y * o0.y + w0.z * o0.z + w0.w * o0.w
            + w1.x * o1.x + w1.y * o1.y + w1.z * o1.z + w1.w * o1.w;
    d += __shfl_xor(d, 1); d += __shfl_xor(d, 2); d += __shfl_xor(d, 4);
    d += __shfl_xor(d, 8); d += __shfl_xor(d, 16); d += __shfl_xor(d, 32);
    if (lane == 0) spb[g] = d + bias[h];
}

// ---------------- kernel 2: W_e -> bf16, K-tiled layout Wt[kt][h][32] ----------------
__global__ void wconv_kernel(const float* __restrict__ W, unsigned short* __restrict__ Wt) {
    int idx = blockIdx.x * 256 + threadIdx.x;
    int e4 = idx * 4;
    int h = e4 >> 10;
    int k = e4 & 1023;
    float4 w = *(const float4*)(W + (size_t)h * 1536 + 512 + k);
    int kt = k >> 5, kk = k & 31;
    ushort4 p;
    p.x = f2bf(w.x); p.y = f2bf(w.y); p.z = f2bf(w.z); p.w = f2bf(w.w);
    *(ushort4*)(Wt + (size_t)kt * (512 * 32) + h * 32 + kk) = p;
}

// ---------------- kernel 3: fused GEMM + tanh + v-dot -> scores[b][s] ----------------
// 512 thr (8 waves). Block tile M=64 (one b, 64 s) x N=512 (full H); wave w: cols
// [w*64, w*64+64), acc = 4x4 16x16 frags = 64 regs. A staged via dbuf LDS (2x4KB,
// one barrier/iter); B frags read straight from L2-resident Wt (contiguous 16B/lane).
__global__ __launch_bounds__(512, 4)
void attn_gemm(const float* __restrict__ enc, const unsigned short* __restrict__ Wt,
               const float* __restrict__ spb, const float* __restrict__ vvec,
               float* __restrict__ scores) {
    __shared__ unsigned short Asm[2 * 64 * 32];  // 8 KB double-buffered
    __shared__ float red[8][64];

    const int tid = threadIdx.x;
    const int w = tid >> 6;
    const int lane = tid & 63;
    const int r = lane & 15;
    const int q = lane >> 4;
    const int b = blockIdx.x >> 5;
    const int s0 = (blockIdx.x & 31) << 6;

    // A staging: thread -> row=tid>>3, 4 floats at k-offset (tid&7)*4
    const int arow = tid >> 3;
    const int akq = tid & 7;
    const float4* aptr = (const float4*)(enc + ((size_t)(b * SS + s0 + arow)) * KK + akq * 4);
    const int st_off = arow * 32 + akq * 4;          // ushort units
    const int rd_off = r * 32 + q * 8;               // frag read base (row r, k q*8)
    const unsigned short* wbase = Wt + (size_t)(w * 64 + r) * 32 + q * 8;

    f32x4 acc[4][4] = {};

    // preload tile 0
    float4 f = aptr[0]; aptr += 8;
    {
        ushort4 p;
        p.x = f2bf(f.x); p.y = f2bf(f.y); p.z = f2bf(f.z); p.w = f2bf(f.w);
        *(ushort4*)(Asm + st_off) = p;
    }
    __syncthreads();

    for (int kt = 0; kt < 31; ++kt) {
        float4 fn = aptr[0]; aptr += 8;  // next tile (32 floats/row per iter)

        const short8* wp = (const short8*)(wbase + (size_t)kt * 16384);
        short8 bf[4];
        #pragma unroll
        for (int nf = 0; nf < 4; ++nf) bf[nf] = wp[nf * 64];   // +16 rows each

        const short8* ap = (const short8*)(Asm + (kt & 1) * 2048 + rd_off);
        short8 af[4];
        #pragma unroll
        for (int mt = 0; mt < 4; ++mt) af[mt] = ap[mt * 64];

        #pragma unroll
        for (int mt = 0; mt < 4; ++mt)
            #pragma unroll
            for (int nf = 0; nf < 4; ++nf)
                acc[mt][nf] = __builtin_amdgcn_mfma_f32_16x16x32_bf16(
                    af[mt], bf[nf], acc[mt][nf], 0, 0, 0);

        ushort4 p;
        p.x = f2bf(fn.x); p.y = f2bf(fn.y); p.z = f2bf(fn.z); p.w = f2bf(fn.w);
        *(ushort4*)(Asm + ((kt + 1) & 1) * 2048 + st_off) = p;
        __syncthreads();
    }
    // last tile (kt=31)
    {
        const short8* wp = (const short8*)(wbase + (size_t)31 * 16384);
        short8 bf[4];
        #pragma unroll
        for (int nf = 0; nf < 4; ++nf) bf[nf] = wp[nf * 64];
        const short8* ap = (const short8*)(Asm + (31 & 1) * 2048 + rd_off);
        short8 af[4];
        #pragma unroll
        for (int mt = 0; mt < 4; ++mt) af[mt] = ap[mt * 64];
        #pragma unroll
        for (int mt = 0; mt < 4; ++mt)
            #pragma unroll
            for (int nf = 0; nf < 4; ++nf)
                acc[mt][nf] = __builtin_amdgcn_mfma_f32_16x16x32_bf16(
                    af[mt], bf[nf], acc[mt][nf], 0, 0, 0);
    }

    // ---- epilogue: partial score = sum over this wave's 64 cols of v[h]*tanh(.+spb)
    float vh[4], sh[4];
    #pragma unroll
    for (int nf = 0; nf < 4; ++nf) {
        int h = w * 64 + nf * 16 + r;
        vh[nf] = vvec[h];
        sh[nf] = spb[b * HH + h];
    }
    float rowacc[4][4] = {};
    #pragma unroll
    for (int mt = 0; mt < 4; ++mt)
        #pragma unroll
        for (int nf = 0; nf < 4; ++nf)
            #pragma unroll
            for (int i = 0; i < 4; ++i) {
                float x = acc[mt][nf][i] + sh[nf];
                rowacc[mt][i] += vh[nf] * fast_tanh(x);
            }
    #pragma unroll
    for (int mt = 0; mt < 4; ++mt)
        #pragma unroll
        for (int i = 0; i < 4; ++i) {
            float t = rowacc[mt][i];
            t += __shfl_xor(t, 1);
            t += __shfl_xor(t, 2);
            t += __shfl_xor(t, 4);
            t += __shfl_xor(t, 8);
            rowacc[mt][i] = t;
        }
    if (r == 0) {
        #pragma unroll
        for (int mt = 0; mt < 4; ++mt)
            #pragma unroll
            for (int i = 0; i < 4; ++i)
                red[w][mt * 16 + q * 4 + i] = rowacc[mt][i];  // row = mt*16+q*4+i
    }
    __syncthreads();
    if (tid < 64) {
        float sum = 0.f;
        #pragma unroll
        for (int ww = 0; ww < 8; ++ww) sum += red[ww][tid];
        scores[b * SS + s0 + tid] = sum;
    }
}

// ---------------- kernel 4: masked softmax over S per batch ----------------
__global__ void softmax_kernel(const float* __restrict__ scores,
                               const int* __restrict__ mask,
                               float* __restrict__ out) {
    __shared__ float red[256];
    int b = blockIdx.x, tid = threadIdx.x;
    float x[8];
    #pragma unroll
    for (int i = 0; i < 8; ++i) {
        int s = tid + i * 256;
        float sc = scores[b * SS + s];
        if (mask[b * SS + s] == 0) sc -= 1000.0f;
        x[i] = sc;
    }
    float mx = x[0];
    #pragma unroll
    for (int i = 1; i < 8; ++i) mx = fmaxf(mx, x[i]);
    red[tid] = mx;
    __syncthreads();
    for (int o = 128; o > 0; o >>= 1) {
        if (tid < o) red[tid] = fmaxf(red[tid], red[tid + o]);
        __syncthreads();
    }
    mx = red[0];
    __syncthreads();
    float e[8], sum = 0.f;
    #pragma unroll
    for (int i = 0; i < 8; ++i) { e[i] = __expf(x[i] - mx); sum += e[i]; }
    red[tid] = sum;
    __syncthreads();
    for (int o = 128; o > 0; o >>= 1) {
        if (tid < o) red[tid] += red[tid + o];
        __syncthreads();
    }
    float inv = 1.0f / red[0];
    #pragma unroll
    for (int i = 0; i < 8; ++i) out[b * SS + tid + i * 256] = e[i] * inv;
}

extern "C" void kernel_launch(void* const* d_in, const int* in_sizes, int n_in,
                              void* d_out, int out_size, void* d_ws, size_t ws_size,
                              hipStream_t stream) {
    const float* out_state = (const float*)d_in[0];   // (32, 512)
    const float* enc       = (const float*)d_in[1];   // (32, 2048, 1024)
    const int*   mask      = (const int*)d_in[2];     // (32, 2048)
    const float* W_attn    = (const float*)d_in[3];   // (512, 1536)
    const float* b_attn    = (const float*)d_in[4];   // (512,)
    const float* vvec      = (const float*)d_in[5];   // (512,)
    float* out = (float*)d_out;                       // (32, 1, 2048)

    char* ws = (char*)d_ws;
    float*          spb    = (float*)ws;                         // 64 KB
    unsigned short* Wt     = (unsigned short*)(ws + 65536);      // 1 MB
    float*          scores = (float*)(ws + 65536 + 1048576);     // 256 KB

    spb_kernel<<<4096, 256, 0, stream>>>(out_state, W_attn, b_attn, spb);
    wconv_kernel<<<512, 256, 0, stream>>>(W_attn, Wt);
    attn_gemm<<<1024, 512, 0, stream>>>(enc, Wt, spb, vvec, scores);
    softmax_kernel<<<32, 256, 0, stream>>>(scores, mask, out);
}